// Round 3
// baseline (132.919 us; speedup 1.0000x reference)
//
#include <hip/hip_runtime.h>
#include <cstdint>

#define T_TOK 16384
#define H 1024
#define F 256
#define D 3
#define DF 768

typedef unsigned short u16;
typedef __attribute__((ext_vector_type(8))) short short8;
typedef __attribute__((ext_vector_type(4))) float floatx4;

__device__ __forceinline__ u16 f2bf(float f) {
  unsigned u = __float_as_uint(f);
  u += 0x7fff + ((u >> 16) & 1);   // round-to-nearest-even
  return (u16)(u >> 16);
}
__device__ __forceinline__ float bf2f(u16 s) {
  return __uint_as_float(((unsigned)s) << 16);
}

__device__ __forceinline__ void gload_lds16(const void* g, void* l) {
  __builtin_amdgcn_global_load_lds(
      reinterpret_cast<const __attribute__((address_space(1))) void*>(
          reinterpret_cast<uintptr_t>(g)),
      reinterpret_cast<__attribute__((address_space(3))) void*>(
          reinterpret_cast<uintptr_t>(l)),
      16, 0, 0);
}

// phase-boundary primitives (8-phase template)
#define FENCE() asm volatile("" ::: "memory")
#define BAR1() do { FENCE(); __builtin_amdgcn_s_barrier(); \
    asm volatile("s_waitcnt lgkmcnt(0)" ::: "memory"); \
    __builtin_amdgcn_sched_barrier(0); } while (0)
#define BAR2() do { FENCE(); __builtin_amdgcn_s_barrier(); FENCE(); } while (0)
#define VMC(n) asm volatile("s_waitcnt vmcnt(" #n ")" ::: "memory")

__device__ __forceinline__ float block_reduce_256(float v, float* red, int tid) {
  #pragma unroll
  for (int o = 32; o > 0; o >>= 1) v += __shfl_xor(v, o);
  __syncthreads();
  if ((tid & 63) == 0) red[tid >> 6] = v;
  __syncthreads();
  return red[0] + red[1] + red[2] + red[3];
}

// ---------------- prep kernels ----------------

__global__ __launch_bounds__(256)
void prep_elem(const float* __restrict__ W1, const float* __restrict__ lng,
               u16* __restrict__ W1p, const float* __restrict__ W2,
               u16* __restrict__ W2r)
{
  int idx = blockIdx.x * 256 + threadIdx.x;
  int stride = gridDim.x * 256;
  for (int i = idx; i < D * F * H; i += stride) {
    int h = i & (H - 1);
    int d = i / (F * H);
    W1p[i] = f2bf(W1[i] * lng[d * H + h]);
  }
  for (int i = idx; i < H * DF; i += stride) {
    int k = i % DF;           // d*F+f
    int hh = i / DF;
    int d = k >> 8;
    int f = k & (F - 1);
    W2r[i] = f2bf(W2[((size_t)d * H + hh) * F + f]);
  }
}

__global__ __launch_bounds__(256)
void prep_dots(const float* __restrict__ W1, const float* __restrict__ lnb,
               const float* __restrict__ b1, const float* __restrict__ W2,
               const float* __restrict__ gv, const float* __restrict__ b2,
               const float* __restrict__ gb, float* __restrict__ b1p,
               float* __restrict__ wg, float* __restrict__ cg)
{
  __shared__ float red[4];
  int d = blockIdx.x >> 8;
  int f = blockIdx.x & 255;
  int tid = threadIdx.x;
  float s1 = 0.f, s2 = 0.f, s3 = 0.f;
  for (int h = tid; h < H; h += 256) {
    float w1v = W1[((size_t)d * F + f) * H + h];
    float gvv = gv[d * H + h];
    s1 += lnb[d * H + h] * w1v;
    s2 += W2[((size_t)d * H + h) * F + f] * gvv;
    if (f == 0) s3 += b2[d * H + h] * gvv;
  }
  float S1 = block_reduce_256(s1, red, tid);
  float S2 = block_reduce_256(s2, red, tid);
  if (tid == 0) {
    b1p[d * F + f] = b1[d * F + f] + S1;
    wg[d * F + f] = S2;
  }
  if (f == 0) {
    float S3 = block_reduce_256(s3, red, tid);
    if (tid == 0) cg[d] = gb[d] + S3;
  }
}

// ---------------- LayerNorm stats + x·gu dots ----------------
__global__ __launch_bounds__(256)
void ln_xu_kernel(const float* __restrict__ x, const float* __restrict__ gu,
                  u16* __restrict__ xn, float* __restrict__ xu)
{
  int t = blockIdx.x;
  int tid = threadIdx.x;
  const float4 xv = *reinterpret_cast<const float4*>(x + (size_t)t * H + tid * 4);
  const float4 g0 = *reinterpret_cast<const float4*>(gu + tid * 4);
  const float4 g1 = *reinterpret_cast<const float4*>(gu + H + tid * 4);
  const float4 g2 = *reinterpret_cast<const float4*>(gu + 2 * H + tid * 4);
  float s  = xv.x + xv.y + xv.z + xv.w;
  float sq = xv.x * xv.x + xv.y * xv.y + xv.z * xv.z + xv.w * xv.w;
  float d0 = xv.x * g0.x + xv.y * g0.y + xv.z * g0.z + xv.w * g0.w;
  float d1 = xv.x * g1.x + xv.y * g1.y + xv.z * g1.z + xv.w * g1.w;
  float d2 = xv.x * g2.x + xv.y * g2.y + xv.z * g2.z + xv.w * g2.w;
  #pragma unroll
  for (int o = 32; o > 0; o >>= 1) {
    s  += __shfl_xor(s, o);  sq += __shfl_xor(sq, o);
    d0 += __shfl_xor(d0, o); d1 += __shfl_xor(d1, o); d2 += __shfl_xor(d2, o);
  }
  __shared__ float red[4][5];
  int w = tid >> 6;
  if ((tid & 63) == 0) {
    red[w][0] = s; red[w][1] = sq; red[w][2] = d0; red[w][3] = d1; red[w][4] = d2;
  }
  __syncthreads();
  float S  = red[0][0] + red[1][0] + red[2][0] + red[3][0];
  float SQ = red[0][1] + red[1][1] + red[2][1] + red[3][1];
  float mu = S * (1.0f / H);
  float var = (SQ - (float)H * mu * mu) * (1.0f / (H - 1));
  float rs = 1.0f / (sqrtf(fmaxf(var, 0.0f)) + 1e-6f);
  ushort4 o4;
  o4.x = f2bf((xv.x - mu) * rs);
  o4.y = f2bf((xv.y - mu) * rs);
  o4.z = f2bf((xv.z - mu) * rs);
  o4.w = f2bf((xv.w - mu) * rs);
  *reinterpret_cast<ushort4*>(xn + (size_t)t * H + tid * 4) = o4;
  if (tid == 0) {
    xu[t]             = red[0][2] + red[1][2] + red[2][2] + red[3][2];
    xu[T_TOK + t]     = red[0][3] + red[1][3] + red[2][3] + red[3][3];
    xu[2 * T_TOK + t] = red[0][4] + red[1][4] + red[2][4] + red[3][4];
  }
}

// ---------------- 8-phase 256x256xBK64 GEMM: C = A·B^T ----------------
// A: [M=16384][K] bf16 (row-major, K-contig). B: [N][K] bf16.
// 8 waves (2M x 4N), per-wave C = 128x64 = acc[8][4] 16x16 frags.
// LDS: 8 slots of 16KB: [dbuf(2)][A/B][khalf(2)], slot = 256 rows x 32 cols.
// Swizzle: byte ^= ((row>>1)&3)<<4 on global source AND ds_read (rule #21).
// Phase quadrant = (m-half, k-half): reads 8/4/8/4 per phase (balanced).
// Stage-map: 1 STG/phase, sigma = [A11+1,B11+1,A00+2,B00+2,A01+2,B01+2,
// A10+3,B10+3]; VMC(6) at odd-phase ends (ledger: every slot forced >=1
// phase before read, stage->force gap 3-4 phases ~1500cy > HBM 900cy).
// Last iteration peeled: no dead stages, tail ledger VMC(6)/(4)/(0).
template <int K, int NLD, int EPI>
__global__ __launch_bounds__(512, 2)
void gemm8(const u16* __restrict__ A, const u16* __restrict__ Bm,
           const float* __restrict__ p0,  // EPI1: b1p  EPI2: x
           const float* __restrict__ p1,  // EPI1: wg   EPI2: gate[3][T]
           const float* __restrict__ p2,  // EPI1: xu   EPI2: b2[3][H]
           const float* __restrict__ p3,  // EPI1: cg   EPI2: unused
           u16* __restrict__ o16,         // EPI1: mid
           float* __restrict__ o32,       // EPI1: gateOut  EPI2: out
           int nBy)
{
  constexpr int NKT = K / 64;
  constexpr int NITER = NKT / 2;
  extern __shared__ u16 LD[];

  const int tid = threadIdx.x, lane = tid & 63, w = tid >> 6;
  const int wm = w >> 2, wn = w & 3, lr = lane & 15, sl = lane >> 4;

  // bijective XCD swizzle (gridDim.x % 8 == 0 for both launches)
  const int nwg = gridDim.x;
  const int wgs = (blockIdx.x & 7) * (nwg >> 3) + (blockIdx.x >> 3);
  const int bx = wgs / nBy, by = wgs % nBy;
  const int m0 = by * 256, n0 = bx * 256;

  const u16* Asrc = A + (size_t)m0 * K;
  const u16* Bsrc = Bm + (size_t)n0 * K;

  // staging: per-thread source offsets (2 chunks of 16B per half-tile)
  const int srow = tid >> 2, ss = tid & 3;
  const int slog = ss ^ ((srow >> 1) & 3);          // swizzled 16B-slot
  const int soff0 = srow * K + slog * 8;            // elems
  const int soff1 = (128 + srow) * K + slog * 8;    // (row>>1)&3 same for +128
  const int ldst0 = w * 512;                        // u16 elems, wave-uniform
  const int ldst1 = 4096 + w * 512;

  // fragment-read offsets (u16 elems within 16KB slot; row stride 32 elems)
  const int xr = (lr >> 1) & 3;
  const int aoff = (wm * 128 + lr) * 32 + ((sl ^ xr) << 3);
  const int boff = (wn * 64 + lr) * 32 + ((sl ^ xr) << 3);

  floatx4 acc[8][4] = {};
  short8 a[4], b[4];

#define SLOTA(d, kh) (LD + ((d)*4 + (kh)) * 8192)
#define SLOTB(d, kh) (LD + ((d)*4 + 2 + (kh)) * 8192)
#define STG(slot, src, T_, KH) do { \
    int kb_ = (T_) * 64 + (KH) * 32; \
    gload_lds16((src) + soff0 + kb_, (slot) + ldst0); \
    gload_lds16((src) + soff1 + kb_, (slot) + ldst1); \
  } while (0)
// load 4 a-frags for m-half mh (rows wm*128 + mh*64 + mf*16 + lr)
#define LDA(d, kh, mh) do { const u16* s_ = SLOTA(d, kh) + aoff + (mh) * 2048; \
    _Pragma("unroll") for (int mf_ = 0; mf_ < 4; ++mf_) \
      a[mf_] = *reinterpret_cast<const short8*>(s_ + mf_ * 512); } while (0)
// load all 4 b-frags (rows wn*64 + nf*16 + lr)
#define LDB(d, kh) do { const u16* s_ = SLOTB(d, kh) + boff; \
    _Pragma("unroll") for (int nf_ = 0; nf_ < 4; ++nf_) \
      b[nf_] = *reinterpret_cast<const short8*>(s_ + nf_ * 512); } while (0)
#define MM(mh) do { __builtin_amdgcn_s_setprio(1); \
    _Pragma("unroll") for (int mf_ = 0; mf_ < 4; ++mf_) \
      _Pragma("unroll") for (int nf_ = 0; nf_ < 4; ++nf_) \
        acc[(mh)*4+mf_][nf_] = __builtin_amdgcn_mfma_f32_16x16x32_bf16( \
            a[mf_], b[nf_], acc[(mh)*4+mf_][nf_], 0, 0, 0); \
    __builtin_amdgcn_s_setprio(0); } while (0)

  // prologue: K0 fully + K1 {A,B kh0}  (6 STG = 12 loads)
  STG(SLOTA(0, 0), Asrc, 0, 0);
  STG(SLOTB(0, 0), Bsrc, 0, 0);
  STG(SLOTA(0, 1), Asrc, 0, 1);
  STG(SLOTB(0, 1), Bsrc, 0, 1);
  STG(SLOTA(1, 0), Asrc, 1, 0);
  STG(SLOTB(1, 0), Bsrc, 1, 0);
  VMC(8);            // force A(0,0), B(0,0)
  BAR2();

  #pragma unroll 1
  for (int i = 0; i < NITER - 1; ++i) {
    const int kt = 2 * i;
    // ph0: (mh0, kh0) dbuf0; stage A(1,1)[kt+1]
    LDA(0, 0, 0); LDB(0, 0);
    STG(SLOTA(1, 1), Asrc, kt + 1, 1);
    BAR1(); MM(0); BAR2();
    // ph1: (mh1, kh0); stage B(1,1)[kt+1]
    LDA(0, 0, 1);
    STG(SLOTB(1, 1), Bsrc, kt + 1, 1);
    BAR1(); MM(1); VMC(6); BAR2();
    // ph2: (mh0, kh1); stage A(0,0)[kt+2]
    LDA(0, 1, 0); LDB(0, 1);
    STG(SLOTA(0, 0), Asrc, kt + 2, 0);
    BAR1(); MM(0); BAR2();
    // ph3: (mh1, kh1); stage B(0,0)[kt+2]
    LDA(0, 1, 1);
    STG(SLOTB(0, 0), Bsrc, kt + 2, 0);
    BAR1(); MM(1); VMC(6); BAR2();
    // ph4: (mh0, kh0) dbuf1; stage A(0,1)[kt+2]
    LDA(1, 0, 0); LDB(1, 0);
    STG(SLOTA(0, 1), Asrc, kt + 2, 1);
    BAR1(); MM(0); BAR2();
    // ph5: (mh1, kh0); stage B(0,1)[kt+2]
    LDA(1, 0, 1);
    STG(SLOTB(0, 1), Bsrc, kt + 2, 1);
    BAR1(); MM(1); VMC(6); BAR2();
    // ph6: (mh0, kh1); stage A(1,0)[kt+3]
    LDA(1, 1, 0); LDB(1, 1);
    STG(SLOTA(1, 0), Asrc, kt + 3, 0);
    BAR1(); MM(0); BAR2();
    // ph7: (mh1, kh1); stage B(1,0)[kt+3]
    LDA(1, 1, 1);
    STG(SLOTB(1, 0), Bsrc, kt + 3, 0);
    BAR1(); MM(1); VMC(6); BAR2();
  }
  // ---- peeled last iteration (kt = NKT-2): only A11,B11 staged ----
  {
    const int kt = NKT - 2;
    LDA(0, 0, 0); LDB(0, 0);
    STG(SLOTA(1, 1), Asrc, kt + 1, 1);
    BAR1(); MM(0); BAR2();
    LDA(0, 0, 1);
    STG(SLOTB(1, 1), Bsrc, kt + 1, 1);
    BAR1(); MM(1); VMC(6); BAR2();
    LDA(0, 1, 0); LDB(0, 1);
    BAR1(); MM(0); BAR2();
    LDA(0, 1, 1);
    BAR1(); MM(1); VMC(4); BAR2();
    LDA(1, 0, 0); LDB(1, 0);
    BAR1(); MM(0); BAR2();
    LDA(1, 0, 1);
    BAR1(); MM(1); VMC(0); BAR2();
    LDA(1, 1, 0); LDB(1, 1);
    BAR1(); MM(0); BAR2();
    LDA(1, 1, 1);
    BAR1(); MM(1); BAR2();
  }
  BAR2();   // LDS now free for epilogue reduction

  // ---- epilogue; C/D frag layout: col=lane&15, row=(lane>>4)*4+i ----
  if constexpr (EPI == 1) {
    // mid = relu(acc + b1p); fused gate: g = sigmoid(Σ mid·wg + xu + cg)
    float b1v[4], wgv[4];
    #pragma unroll
    for (int nf = 0; nf < 4; ++nf) {
      int col = n0 + wn * 64 + nf * 16 + lr;
      b1v[nf] = p0[col];
      wgv[nf] = p1[col];
    }
    float* red = (float*)LD;   // [4 wn][256 rows]
    #pragma unroll
    for (int mf = 0; mf < 8; ++mf)
      #pragma unroll
      for (int i2 = 0; i2 < 4; ++i2) {
        float p = 0.f;
        #pragma unroll
        for (int nf = 0; nf < 4; ++nf)
          p += fmaxf(acc[mf][nf][i2] + b1v[nf], 0.f) * wgv[nf];
        p += __shfl_xor(p, 1); p += __shfl_xor(p, 2);
        p += __shfl_xor(p, 4); p += __shfl_xor(p, 8);
        if (lr == 0) red[wn * 256 + wm * 128 + mf * 16 + sl * 4 + i2] = p;
      }
    __syncthreads();
    const int d = bx;          // block n-tile == domain
    const float cgv = p3[d];
    #pragma unroll
    for (int mf = 0; mf < 8; ++mf)
      #pragma unroll
      for (int i2 = 0; i2 < 4; ++i2) {
        int rl = wm * 128 + mf * 16 + sl * 4 + i2;
        int r = m0 + rl;
        float logit = red[rl] + red[256 + rl] + red[512 + rl] + red[768 + rl]
                    + p2[(size_t)d * T_TOK + r] + cgv;
        float g = 1.f / (1.f + expf(-logit));
        #pragma unroll
        for (int nf = 0; nf < 4; ++nf) {
          int col = n0 + wn * 64 + nf * 16 + lr;
          float v = fmaxf(acc[mf][nf][i2] + b1v[nf], 0.f);
          o16[(size_t)r * NLD + col] = f2bf(v * g);
        }
        if (lr == 0 && wn == 0) o32[(size_t)d * T_TOK + r] = g;
      }
  } else {
    // out = acc + 2x + Σ_d g_d·b2[d]
    float b2v[3][4];
    #pragma unroll
    for (int dd = 0; dd < 3; ++dd)
      #pragma unroll
      for (int nf = 0; nf < 4; ++nf)
        b2v[dd][nf] = p2[dd * H + n0 + wn * 64 + nf * 16 + lr];
    #pragma unroll
    for (int mf = 0; mf < 8; ++mf)
      #pragma unroll
      for (int i2 = 0; i2 < 4; ++i2) {
        int r = m0 + wm * 128 + mf * 16 + sl * 4 + i2;
        float g0 = p1[r], g1 = p1[T_TOK + r], g2 = p1[2 * T_TOK + r];
        const float* xrow = p0 + (size_t)r * H;
        float* orow = o32 + (size_t)r * NLD;
        #pragma unroll
        for (int nf = 0; nf < 4; ++nf) {
          int col = n0 + wn * 64 + nf * 16 + lr;
          orow[col] = acc[mf][nf][i2] + 2.f * xrow[col]
                    + g0 * b2v[0][nf] + g1 * b2v[1][nf] + g2 * b2v[2][nf];
        }
      }
  }
#undef SLOTA
#undef SLOTB
#undef STG
#undef LDA
#undef LDB
#undef MM
}

// ---------------- launch ----------------

extern "C" void kernel_launch(void* const* d_in, const int* in_sizes, int n_in,
                              void* d_out, int out_size, void* d_ws, size_t ws_size,
                              hipStream_t stream) {
  const float* x   = (const float*)d_in[0];
  const float* lng = (const float*)d_in[1];
  const float* lnb = (const float*)d_in[2];
  const float* W1  = (const float*)d_in[3];
  const float* b1  = (const float*)d_in[4];
  const float* W2  = (const float*)d_in[5];
  const float* b2  = (const float*)d_in[6];
  const float* gu  = (const float*)d_in[7];
  const float* gv  = (const float*)d_in[8];
  const float* gb  = (const float*)d_in[9];
  float* out = (float*)d_out;

  char* ws = (char*)d_ws;
  u16* xn   = (u16*)ws;  ws += (size_t)T_TOK * H * 2;     // 32 MB
  u16* mid  = (u16*)ws;  ws += (size_t)T_TOK * DF * 2;    // 24 MB
  u16* W1p  = (u16*)ws;  ws += (size_t)DF * H * 2;
  u16* W2r  = (u16*)ws;  ws += (size_t)H * DF * 2;
  float* b1p  = (float*)ws;  ws += DF * 4;
  float* wg   = (float*)ws;  ws += DF * 4;
  float* cg   = (float*)ws;  ws += 256;
  float* xu   = (float*)ws;  ws += (size_t)D * T_TOK * 4;
  float* gate = (float*)ws;  ws += (size_t)D * T_TOK * 4;
  (void)ws_size; (void)in_sizes; (void)n_in; (void)out_size;

  hipFuncSetAttribute(reinterpret_cast<const void*>(&gemm8<1024, DF, 1>),
                      hipFuncAttributeMaxDynamicSharedMemorySize, 131072);
  hipFuncSetAttribute(reinterpret_cast<const void*>(&gemm8<768, H, 2>),
                      hipFuncAttributeMaxDynamicSharedMemorySize, 131072);

  prep_elem<<<3072, 256, 0, stream>>>(W1, lng, W1p, W2, W2r);
  prep_dots<<<DF, 256, 0, stream>>>(W1, lnb, b1, W2, gv, b2, gb, b1p, wg, cg);
  ln_xu_kernel<<<T_TOK, 256, 0, stream>>>(x, gu, xn, xu);
  // GEMM1: [16384 x 768] = xn[16384x1024] · W1p[768x1024]^T, +gate fusion
  gemm8<1024, DF, 1><<<64 * 3, 512, 131072, stream>>>(
      xn, W1p, b1p, wg, xu, cg, mid, gate, 64);
  // GEMM2: out[16384x1024] = mid[16384x768] · W2r[1024x768]^T + epilogue
  gemm8<768, H, 2><<<64 * 4, 512, 131072, stream>>>(
      mid, W2r, x, gate, b2, nullptr, nullptr, out, 64);
}

// Round 4
// 131.216 us; speedup vs baseline: 1.0130x; 1.0130x over previous
//
#include <hip/hip_runtime.h>
#include <cstdint>

#define T_TOK 16384
#define H 1024
#define F 256
#define D 3
#define DF 768

typedef unsigned short u16;
typedef __attribute__((ext_vector_type(8))) short short8;
typedef __attribute__((ext_vector_type(4))) float floatx4;

__device__ __forceinline__ u16 f2bf(float f) {
  unsigned u = __float_as_uint(f);
  u += 0x7fff + ((u >> 16) & 1);   // round-to-nearest-even
  return (u16)(u >> 16);
}
__device__ __forceinline__ float bf2f(u16 s) {
  return __uint_as_float(((unsigned)s) << 16);
}

__device__ __forceinline__ void gload_lds16(const void* g, void* l) {
  __builtin_amdgcn_global_load_lds(
      reinterpret_cast<const __attribute__((address_space(1))) void*>(
          reinterpret_cast<uintptr_t>(g)),
      reinterpret_cast<__attribute__((address_space(3))) void*>(
          reinterpret_cast<uintptr_t>(l)),
      16, 0, 0);
}

#define FENCE() asm volatile("" ::: "memory")
#define BAR1() do { FENCE(); __builtin_amdgcn_s_barrier(); \
    asm volatile("s_waitcnt lgkmcnt(0)" ::: "memory"); \
    __builtin_amdgcn_sched_barrier(0); } while (0)
#define BAR2() do { FENCE(); __builtin_amdgcn_s_barrier(); FENCE(); } while (0)
#define VMC(n) asm volatile("s_waitcnt vmcnt(" #n ")" ::: "memory")

__device__ __forceinline__ float block_reduce_256(float v, float* red, int tid) {
  #pragma unroll
  for (int o = 32; o > 0; o >>= 1) v += __shfl_xor(v, o);
  __syncthreads();
  if ((tid & 63) == 0) red[tid >> 6] = v;
  __syncthreads();
  return red[0] + red[1] + red[2] + red[3];
}

// ---------------- prep kernels ----------------

__global__ __launch_bounds__(256)
void prep_elem(const float* __restrict__ W1, const float* __restrict__ lng,
               u16* __restrict__ W1p, const float* __restrict__ W2,
               u16* __restrict__ W2r)
{
  int idx = blockIdx.x * 256 + threadIdx.x;
  int stride = gridDim.x * 256;
  for (int i = idx; i < D * F * H; i += stride) {
    int h = i & (H - 1);
    int d = i / (F * H);
    W1p[i] = f2bf(W1[i] * lng[d * H + h]);
  }
  for (int i = idx; i < H * DF; i += stride) {
    int k = i % DF;           // d*F+f
    int hh = i / DF;
    int d = k >> 8;
    int f = k & (F - 1);
    W2r[i] = f2bf(W2[((size_t)d * H + hh) * F + f]);
  }
}

__global__ __launch_bounds__(256)
void prep_dots(const float* __restrict__ W1, const float* __restrict__ lnb,
               const float* __restrict__ b1, const float* __restrict__ W2,
               const float* __restrict__ gv, const float* __restrict__ b2,
               const float* __restrict__ gb, float* __restrict__ b1p,
               float* __restrict__ wg, float* __restrict__ cg)
{
  __shared__ float red[4];
  int d = blockIdx.x >> 8;
  int f = blockIdx.x & 255;
  int tid = threadIdx.x;
  float s1 = 0.f, s2 = 0.f, s3 = 0.f;
  for (int h = tid; h < H; h += 256) {
    float w1v = W1[((size_t)d * F + f) * H + h];
    float gvv = gv[d * H + h];
    s1 += lnb[d * H + h] * w1v;
    s2 += W2[((size_t)d * H + h) * F + f] * gvv;
    if (f == 0) s3 += b2[d * H + h] * gvv;
  }
  float S1 = block_reduce_256(s1, red, tid);
  float S2 = block_reduce_256(s2, red, tid);
  if (tid == 0) {
    b1p[d * F + f] = b1[d * F + f] + S1;
    wg[d * F + f] = S2;
  }
  if (f == 0) {
    float S3 = block_reduce_256(s3, red, tid);
    if (tid == 0) cg[d] = gb[d] + S3;
  }
}

// ---------------- LayerNorm stats + x·gu dots ----------------
__global__ __launch_bounds__(256)
void ln_xu_kernel(const float* __restrict__ x, const float* __restrict__ gu,
                  u16* __restrict__ xn, float* __restrict__ xu)
{
  int t = blockIdx.x;
  int tid = threadIdx.x;
  const float4 xv = *reinterpret_cast<const float4*>(x + (size_t)t * H + tid * 4);
  const float4 g0 = *reinterpret_cast<const float4*>(gu + tid * 4);
  const float4 g1 = *reinterpret_cast<const float4*>(gu + H + tid * 4);
  const float4 g2 = *reinterpret_cast<const float4*>(gu + 2 * H + tid * 4);
  float s  = xv.x + xv.y + xv.z + xv.w;
  float sq = xv.x * xv.x + xv.y * xv.y + xv.z * xv.z + xv.w * xv.w;
  float d0 = xv.x * g0.x + xv.y * g0.y + xv.z * g0.z + xv.w * g0.w;
  float d1 = xv.x * g1.x + xv.y * g1.y + xv.z * g1.z + xv.w * g1.w;
  float d2 = xv.x * g2.x + xv.y * g2.y + xv.z * g2.z + xv.w * g2.w;
  #pragma unroll
  for (int o = 32; o > 0; o >>= 1) {
    s  += __shfl_xor(s, o);  sq += __shfl_xor(sq, o);
    d0 += __shfl_xor(d0, o); d1 += __shfl_xor(d1, o); d2 += __shfl_xor(d2, o);
  }
  __shared__ float red[4][5];
  int w = tid >> 6;
  if ((tid & 63) == 0) {
    red[w][0] = s; red[w][1] = sq; red[w][2] = d0; red[w][3] = d1; red[w][4] = d2;
  }
  __syncthreads();
  float S  = red[0][0] + red[1][0] + red[2][0] + red[3][0];
  float SQ = red[0][1] + red[1][1] + red[2][1] + red[3][1];
  float mu = S * (1.0f / H);
  float var = (SQ - (float)H * mu * mu) * (1.0f / (H - 1));
  float rs = 1.0f / (sqrtf(fmaxf(var, 0.0f)) + 1e-6f);
  ushort4 o4;
  o4.x = f2bf((xv.x - mu) * rs);
  o4.y = f2bf((xv.y - mu) * rs);
  o4.z = f2bf((xv.z - mu) * rs);
  o4.w = f2bf((xv.w - mu) * rs);
  *reinterpret_cast<ushort4*>(xn + (size_t)t * H + tid * 4) = o4;
  if (tid == 0) {
    xu[t]             = red[0][2] + red[1][2] + red[2][2] + red[3][2];
    xu[T_TOK + t]     = red[0][3] + red[1][3] + red[2][3] + red[3][3];
    xu[2 * T_TOK + t] = red[0][4] + red[1][4] + red[2][4] + red[3][4];
  }
}

// ---------------- ring-3 128x256xBK32 GEMM: C = A·B^T ----------------
// 8 waves (2m x 4n), per-wave C = 64x64 = acc[4][4] 16x16 frags.
// LDS: 3 slots x 24KB, slot = A[128][32] + B[256][32] bf16 (linear; every
// wave ds_read is a contiguous 1KB block -> conflict-free, no swizzle).
// Per phase (1 K-slice of 32): 8 ds_read_b128 + 16 MFMA + stage slice p+2
// (3 gload_lds16/thread) + BAR1/VMC(3)/BAR2. Ring: read slot p%3, write
// (p+2)%3 — previous occupant last read at phase p-1 (barrier-protected).
// Ledger: end of phase p outstanding = slices p+1,p+2 (3 each) -> VMC(3)
// forces p+1. Tail: NS-3 stages last slice; NS-2 VMC(0); NS-1 plain.
// 72KB LDS + 128-VGPR cap -> 2 independent blocks/CU (16 waves, 4/SIMD).
template <int K, int NLD, int EPI>
__global__ __launch_bounds__(512, 4)
void gemm3s(const u16* __restrict__ A, const u16* __restrict__ Bm,
            const float* __restrict__ p0,  // EPI1: b1p  EPI2: x
            const float* __restrict__ p1,  // EPI1: wg   EPI2: gate[3][T]
            const float* __restrict__ p2,  // EPI1: xu   EPI2: b2[3][H]
            const float* __restrict__ p3,  // EPI1: cg   EPI2: unused
            u16* __restrict__ o16,         // EPI1: mid
            float* __restrict__ o32,       // EPI1: gateOut  EPI2: out
            int nBx)
{
  constexpr int NS = K / 32;          // K-slices
  constexpr int SLOT = 12288;         // u16 elems per slot (24KB)
  extern __shared__ u16 LD[];

  const int tid = threadIdx.x, lane = tid & 63, w = tid >> 6;
  const int wm = w >> 2, wn = w & 3, lr = lane & 15, sl = lane >> 4;

  // bijective XCD swizzle (gridDim.x % 8 == 0); bx fastest so A-sharers
  // are XCD-adjacent (L2 reuse of the A panel)
  const int nwg = gridDim.x;
  const int wgs = (blockIdx.x & 7) * (nwg >> 3) + (blockIdx.x >> 3);
  const int bx = wgs % nBx, by = wgs / nBx;
  const int m0 = by * 128, n0 = bx * 256;

  const u16* Asrc = A + (size_t)m0 * K;
  const u16* Bsrc = Bm + (size_t)n0 * K;

  // staging source offsets (16B chunks; row = tid>>2, chunk = tid&3)
  const int goff0 = (tid >> 2) * K + (tid & 3) * 8;
  const int goff1 = goff0 + 128 * K;
  const int w512 = w * 512;           // wave-uniform LDS dest base (elems)

  // read offsets (contiguous 1KB per wave per frag-block)
  const int sl8 = sl * 8;
  const int aoff = (wm * 64 + lr) * 32 + sl8;          // A rows @ slot+0
  const int boff = 4096 + (wn * 64 + lr) * 32 + sl8;   // B rows @ slot+4096

  floatx4 acc[4][4] = {};
  short8 a[4], b[4];

#define STG(P, ks) do { \
    gload_lds16(Asrc + goff0 + (ks) * 32, (P) + w512); \
    gload_lds16(Bsrc + goff0 + (ks) * 32, (P) + 4096 + w512); \
    gload_lds16(Bsrc + goff1 + (ks) * 32, (P) + 8192 + w512); \
  } while (0)
#define LDAB(P) do { const u16* sa_ = (P) + aoff; const u16* sb_ = (P) + boff; \
    _Pragma("unroll") for (int i_ = 0; i_ < 4; ++i_) { \
      a[i_] = *reinterpret_cast<const short8*>(sa_ + i_ * 512); \
      b[i_] = *reinterpret_cast<const short8*>(sb_ + i_ * 512); } } while (0)
#define MM() do { __builtin_amdgcn_s_setprio(1); \
    _Pragma("unroll") for (int mf_ = 0; mf_ < 4; ++mf_) \
      _Pragma("unroll") for (int nf_ = 0; nf_ < 4; ++nf_) \
        acc[mf_][nf_] = __builtin_amdgcn_mfma_f32_16x16x32_bf16( \
            a[mf_], b[nf_], acc[mf_][nf_], 0, 0, 0); \
    __builtin_amdgcn_s_setprio(0); } while (0)

  // prologue: stage slices 0,1
  STG(LD, 0);
  STG(LD + SLOT, 1);
  VMC(3);               // force slice 0
  BAR2();

  int s = 0;
  #pragma unroll 3
  for (int p = 0; p < NS - 3; ++p) {
    u16* cur = LD + s * SLOT;
    int s2 = s + 2; if (s2 >= 3) s2 -= 3;
    LDAB(cur);
    STG(LD + s2 * SLOT, p + 2);
    BAR1(); MM(); VMC(3); BAR2();
    ++s; if (s == 3) s = 0;
  }
  {   // p = NS-3: stage last slice NS-1
    u16* cur = LD + s * SLOT;
    int s2 = s + 2; if (s2 >= 3) s2 -= 3;
    LDAB(cur);
    STG(LD + s2 * SLOT, NS - 1);
    BAR1(); MM(); VMC(3); BAR2();
    ++s; if (s == 3) s = 0;
  }
  {   // p = NS-2: drain
    u16* cur = LD + s * SLOT;
    LDAB(cur);
    BAR1(); MM(); VMC(0); BAR2();
    ++s; if (s == 3) s = 0;
  }
  {   // p = NS-1
    u16* cur = LD + s * SLOT;
    LDAB(cur);
    BAR1(); MM(); BAR2();
  }
  BAR2();   // LDS free for epilogue

  // ---- epilogue; C/D frag layout: col=lane&15, row=(lane>>4)*4+i ----
  if constexpr (EPI == 1) {
    // mid = relu(acc + b1p); fused gate: g = sigmoid(Σ mid·wg + xu + cg)
    float b1v[4], wgv[4];
    #pragma unroll
    for (int nf = 0; nf < 4; ++nf) {
      int col = n0 + wn * 64 + nf * 16 + lr;
      b1v[nf] = p0[col];
      wgv[nf] = p1[col];
    }
    float* red = (float*)LD;   // [4 wn][128 rows]
    #pragma unroll
    for (int mf = 0; mf < 4; ++mf)
      #pragma unroll
      for (int i2 = 0; i2 < 4; ++i2) {
        float p = 0.f;
        #pragma unroll
        for (int nf = 0; nf < 4; ++nf)
          p += fmaxf(acc[mf][nf][i2] + b1v[nf], 0.f) * wgv[nf];
        p += __shfl_xor(p, 1); p += __shfl_xor(p, 2);
        p += __shfl_xor(p, 4); p += __shfl_xor(p, 8);
        if (lr == 0) red[wn * 128 + wm * 64 + mf * 16 + sl * 4 + i2] = p;
      }
    __syncthreads();
    const int d = bx;          // block n-tile == domain
    const float cgv = p3[d];
    #pragma unroll
    for (int mf = 0; mf < 4; ++mf)
      #pragma unroll
      for (int i2 = 0; i2 < 4; ++i2) {
        int rl = wm * 64 + mf * 16 + sl * 4 + i2;
        int r = m0 + rl;
        float logit = red[rl] + red[128 + rl] + red[256 + rl] + red[384 + rl]
                    + p2[(size_t)d * T_TOK + r] + cgv;
        float g = 1.f / (1.f + expf(-logit));
        #pragma unroll
        for (int nf = 0; nf < 4; ++nf) {
          int col = n0 + wn * 64 + nf * 16 + lr;
          float v = fmaxf(acc[mf][nf][i2] + b1v[nf], 0.f);
          o16[(size_t)r * NLD + col] = f2bf(v * g);
        }
        if (lr == 0 && wn == 0) o32[(size_t)d * T_TOK + r] = g;
      }
  } else {
    // out = acc + 2x + Σ_d g_d·b2[d]
    float b2v[3][4];
    #pragma unroll
    for (int dd = 0; dd < 3; ++dd)
      #pragma unroll
      for (int nf = 0; nf < 4; ++nf)
        b2v[dd][nf] = p2[dd * H + n0 + wn * 64 + nf * 16 + lr];
    #pragma unroll
    for (int mf = 0; mf < 4; ++mf)
      #pragma unroll
      for (int i2 = 0; i2 < 4; ++i2) {
        int r = m0 + wm * 64 + mf * 16 + sl * 4 + i2;
        float g0 = p1[r], g1 = p1[T_TOK + r], g2 = p1[2 * T_TOK + r];
        const float* xrow = p0 + (size_t)r * H;
        float* orow = o32 + (size_t)r * NLD;
        #pragma unroll
        for (int nf = 0; nf < 4; ++nf) {
          int col = n0 + wn * 64 + nf * 16 + lr;
          orow[col] = acc[mf][nf][i2] + 2.f * xrow[col]
                    + g0 * b2v[0][nf] + g1 * b2v[1][nf] + g2 * b2v[2][nf];
        }
      }
  }
#undef STG
#undef LDAB
#undef MM
}

// ---------------- launch ----------------

extern "C" void kernel_launch(void* const* d_in, const int* in_sizes, int n_in,
                              void* d_out, int out_size, void* d_ws, size_t ws_size,
                              hipStream_t stream) {
  const float* x   = (const float*)d_in[0];
  const float* lng = (const float*)d_in[1];
  const float* lnb = (const float*)d_in[2];
  const float* W1  = (const float*)d_in[3];
  const float* b1  = (const float*)d_in[4];
  const float* W2  = (const float*)d_in[5];
  const float* b2  = (const float*)d_in[6];
  const float* gu  = (const float*)d_in[7];
  const float* gv  = (const float*)d_in[8];
  const float* gb  = (const float*)d_in[9];
  float* out = (float*)d_out;

  char* ws = (char*)d_ws;
  u16* xn   = (u16*)ws;  ws += (size_t)T_TOK * H * 2;     // 32 MB
  u16* mid  = (u16*)ws;  ws += (size_t)T_TOK * DF * 2;    // 24 MB
  u16* W1p  = (u16*)ws;  ws += (size_t)DF * H * 2;
  u16* W2r  = (u16*)ws;  ws += (size_t)H * DF * 2;
  float* b1p  = (float*)ws;  ws += DF * 4;
  float* wg   = (float*)ws;  ws += DF * 4;
  float* cg   = (float*)ws;  ws += 256;
  float* xu   = (float*)ws;  ws += (size_t)D * T_TOK * 4;
  float* gate = (float*)ws;  ws += (size_t)D * T_TOK * 4;
  (void)ws_size; (void)in_sizes; (void)n_in; (void)out_size;

  hipFuncSetAttribute(reinterpret_cast<const void*>(&gemm3s<1024, DF, 1>),
                      hipFuncAttributeMaxDynamicSharedMemorySize, 73728);
  hipFuncSetAttribute(reinterpret_cast<const void*>(&gemm3s<768, H, 2>),
                      hipFuncAttributeMaxDynamicSharedMemorySize, 73728);

  prep_elem<<<3072, 256, 0, stream>>>(W1, lng, W1p, W2, W2r);
  prep_dots<<<DF, 256, 0, stream>>>(W1, lnb, b1, W2, gv, b2, gb, b1p, wg, cg);
  ln_xu_kernel<<<T_TOK, 256, 0, stream>>>(x, gu, xn, xu);
  // GEMM1: mid[16384x768] = xn[16384x1024] · W1p[768x1024]^T  (+gate)
  gemm3s<1024, DF, 1><<<128 * 3, 512, 73728, stream>>>(
      xn, W1p, b1p, wg, xu, cg, mid, gate, 3);
  // GEMM2: out[16384x1024] = mid[16384x768] · W2r[1024x768]^T (+epilogue)
  gemm3s<768, H, 2><<<128 * 4, 512, 73728, stream>>>(
      mid, W2r, x, gate, b2, nullptr, nullptr, out, 4);
}